// Round 3
// baseline (283.705 us; speedup 1.0000x reference)
//
#include <hip/hip_runtime.h>

#define BB 4
#define CC 256
#define DD 32
#define SS 4096

typedef __bf16 bf16;
typedef __bf16 bf16x8 __attribute__((ext_vector_type(8)));
typedef __bf16 bf16x4 __attribute__((ext_vector_type(4)));
typedef float f32x4 __attribute__((ext_vector_type(4)));
typedef unsigned int u32;
typedef unsigned short u16;

// workspace layout (bf16 elements):
//  q:  [2][BB][SS][DD]  off 0         (pos-major, 32 d inner)
//  k:  [2][BB][SS][DD]  off 1048576
//  v:  [2][BB][CC][SS]  off 2097152   (c-major, pos inner)
//  wb: [320][CC]        off 10485760  (bf16 Wq|Wk|Wv stacked)
#define Q_OFF  0
#define K_OFF  1048576
#define V_OFF  2097152
#define WB_OFF 10485760

static __device__ __forceinline__ u32 pack2(float lo, float hi) {
    bf16 a = (bf16)lo, b = (bf16)hi;
    u16 ua = __builtin_bit_cast(u16, a), ub = __builtin_bit_cast(u16, b);
    return (u32)ua | ((u32)ub << 16);
}

// LDS-only barrier: drain ds ops, sync, but let global loads stay in flight
// (__syncthreads emits s_waitcnt vmcnt(0) which defeats register prefetch).
static __device__ __forceinline__ void bar_lds() {
    asm volatile("s_waitcnt lgkmcnt(0)" ::: "memory");
    __builtin_amdgcn_s_barrier();
    asm volatile("" ::: "memory");
}

// ------------------------------------------------- W fp32 -> bf16 [320][256]
__global__ __launch_bounds__(256) void convert_w_kernel(
    const float* __restrict__ Wq, const float* __restrict__ Wk,
    const float* __restrict__ Wv, bf16* __restrict__ wb)
{
    const int gid = blockIdx.x*256 + threadIdx.x;    // 40 blocks -> 10240
    const int idx = gid*8;
    const int o = idx >> 8, cc = idx & 255;
    const float* row = (o < 32) ? (Wq + (size_t)o*CC)
                     : (o < 64) ? (Wk + (size_t)(o-32)*CC)
                                : (Wv + (size_t)(o-64)*CC);
    const float4 a = *(const float4*)(row + cc);
    const float4 c = *(const float4*)(row + cc + 4);
    bf16x8 pk;
    pk[0]=(bf16)a.x; pk[1]=(bf16)a.y; pk[2]=(bf16)a.z; pk[3]=(bf16)a.w;
    pk[4]=(bf16)c.x; pk[5]=(bf16)c.y; pk[6]=(bf16)c.z; pk[7]=(bf16)c.w;
    *(bf16x8*)(wb + idx) = pk;
}

// ------------------------------------------------- fused q,k,v projection (MFMA)
// C[pos][o] = sum_cc X[cc][pos]*W[o][cc] + bias;  o: 0-31 q, 32-63 k, 64-319 v
// Double-buffered xT + register X-prefetch; bar_lds (no vmcnt drain) keeps the
// global prefetches in flight across the per-chunk barrier.
__global__ __launch_bounds__(256, 2) void proj_all_kernel(
    const float* __restrict__ x, const float* __restrict__ y,
    const bf16* __restrict__ wb,
    const float* __restrict__ bq, const float* __restrict__ bk,
    const float* __restrict__ bv,
    bf16* __restrict__ qout, bf16* __restrict__ kout, bf16* __restrict__ vout)
{
    // xT: [2][64 pos][40 bf16] (row 80 B, 16B-aligned)
    __shared__ __align__(16) char smem[2*5120];
    bf16* xT  = (bf16*)smem;
    u32*  xTw = (u32*)smem;

    const int t    = threadIdx.x;
    const int lane = t & 63;
    const int w    = t >> 6;
    const int ln   = lane & 15;
    const int quad = lane >> 4;

    const int bid  = blockIdx.x;
    const int dirb = bid & 7;
    const int src  = dirb >> 2;
    const int b    = dirb & 3;
    const int i0   = (bid >> 3) * 64;
    const float* in = src ? y : x;
    const float* xbase = in + (size_t)b*CC*SS + i0;

    const int cp = t >> 4;            // cc-pair 0..15 -> cc {2cp, 2cp+1}
    const int pq = (t & 15) * 4;      // pos 0..60

    float bias[5];
    #pragma unroll
    for (int nbl = 0; nbl < 5; ++nbl) {
        const int o = 80*w + nbl*16 + ln;
        bias[nbl] = (o < 32) ? bq[o] : (o < 64) ? bk[o-32] : bv[o-64];
    }
    f32x4 acc[4][5];
    #pragma unroll
    for (int mb = 0; mb < 4; ++mb)
        #pragma unroll
        for (int nbl = 0; nbl < 5; ++nbl)
            acc[mb][nbl] = (f32x4){bias[nbl], bias[nbl], bias[nbl], bias[nbl]};

    const bf16* wrow = wb + (size_t)(80*w + ln)*CC + quad*8;
    bf16x8 bf[5];
    #pragma unroll
    for (int nbl = 0; nbl < 5; ++nbl)
        bf[nbl] = *(const bf16x8*)(wrow + (size_t)nbl*16*CC);

    // stage chunk 0 into buf0
    {
        const float* r0 = xbase + (size_t)(2*cp)*SS + pq;
        const float4 a0 = *(const float4*)r0;
        const float4 a1 = *(const float4*)(r0 + SS);
        xTw[(pq+0)*20 + cp] = pack2(a0.x, a1.x);
        xTw[(pq+1)*20 + cp] = pack2(a0.y, a1.y);
        xTw[(pq+2)*20 + cp] = pack2(a0.z, a1.z);
        xTw[(pq+3)*20 + cp] = pack2(a0.w, a1.w);
    }
    // prefetch chunk 1 into regs
    float4 a0, a1;
    {
        const float* r1 = xbase + (size_t)(32 + 2*cp)*SS + pq;
        a0 = *(const float4*)r1;
        a1 = *(const float4*)(r1 + SS);
    }
    bar_lds();

    for (int n = 0; n < 8; ++n) {
        bf16x8 af[4];
        #pragma unroll
        for (int mb = 0; mb < 4; ++mb)
            af[mb] = *(const bf16x8*)(xT + (n&1)*2560 + (mb*16 + ln)*40 + quad*8);
        // write prefetched chunk n+1 into other buffer
        if (n < 7) {
            u32* dst = xTw + ((n+1)&1)*1280;
            dst[(pq+0)*20 + cp] = pack2(a0.x, a1.x);
            dst[(pq+1)*20 + cp] = pack2(a0.y, a1.y);
            dst[(pq+2)*20 + cp] = pack2(a0.z, a1.z);
            dst[(pq+3)*20 + cp] = pack2(a0.w, a1.w);
        }
        // prefetch chunk n+2 regs (wrap keeps loads in-bounds; redundant at tail)
        {
            const int cc2 = ((n+2)*32) & 255;
            const float* r2 = xbase + (size_t)(cc2 + 2*cp)*SS + pq;
            a0 = *(const float4*)r2;
            a1 = *(const float4*)(r2 + SS);
        }
        #pragma unroll
        for (int mb = 0; mb < 4; ++mb)
            #pragma unroll
            for (int nbl = 0; nbl < 5; ++nbl)
                acc[mb][nbl] = __builtin_amdgcn_mfma_f32_16x16x32_bf16(
                                   af[mb], bf[nbl], acc[mb][nbl], 0, 0, 0);
        // prefetch next W chunk
        const int ccn = ((n+1)*32) & 255;
        #pragma unroll
        for (int nbl = 0; nbl < 5; ++nbl)
            bf[nbl] = *(const bf16x8*)(wrow + (size_t)nbl*16*CC + ccn);
        bar_lds();
    }

    bf16* qo = qout + (size_t)(src*BB + b)*SS*DD;
    bf16* ko = kout + (size_t)(src*BB + b)*SS*DD;
    bf16* vo = vout + (size_t)(src*BB + b)*CC*SS;
    #pragma unroll
    for (int nbl = 0; nbl < 5; ++nbl) {
        const int o = 80*w + nbl*16 + ln;
        if (o < 32) {
            #pragma unroll
            for (int mb = 0; mb < 4; ++mb)
                #pragma unroll
                for (int r = 0; r < 4; ++r)
                    qo[(size_t)(i0 + mb*16 + quad*4 + r)*DD + o] = (bf16)acc[mb][nbl][r];
        } else if (o < 64) {
            #pragma unroll
            for (int mb = 0; mb < 4; ++mb)
                #pragma unroll
                for (int r = 0; r < 4; ++r)
                    ko[(size_t)(i0 + mb*16 + quad*4 + r)*DD + (o-32)] = (bf16)acc[mb][nbl][r];
        } else {
            const int c = o - 64;
            #pragma unroll
            for (int mb = 0; mb < 4; ++mb) {
                bf16x4 pk;
                #pragma unroll
                for (int r = 0; r < 4; ++r) pk[r] = (bf16)acc[mb][nbl][r];
                *(bf16x4*)(vo + (size_t)c*SS + i0 + mb*16 + quad*4) = pk;
            }
        }
    }
}

// ------------------------------------------------- attention (c-split, 4 blk/CU)
// Block: 64 queries x 128 c (c-half per block) -> grid 1024 = 4 blocks/CU =
// 16 waves/CU (was grid-limited at 2 blocks/CU; every pipe <25% busy, pure
// latency). Wave w: S^T for queries [16w,16w+16) (duplicated across the c-half
// pair — VALU is cheap), PV c-range [c0+32w, c0+32w+32). P in LDS [2][64][64]
// XOR-swizzled. kf/vf single-buffered (load-after-use, ~1-iter distance) to fit
// VGPR<=128 for 4 waves/SIMD. exp2-form softmax (fma+exp, no clamp: |S|<~30).
#define SM_M  16.0f
#define L2E   1.4426950408889634f
#define SM_C  (SM_M * L2E)

__global__ __launch_bounds__(256, 4) void attn_kernel(
    const bf16* __restrict__ qg, const bf16* __restrict__ kg,
    const bf16* __restrict__ vg, float* __restrict__ out)
{
    __shared__ __align__(16) char smem[16640];
    bf16*  p_s = (bf16*)smem;               // [2][64][64] swizzled
    float* l_s = (float*)(smem + 16384);    // [64]

    const int t    = threadIdx.x;
    const int lane = t & 63;
    const int w    = t >> 6;
    const int ln   = lane & 15;
    const int quad = lane >> 4;

    const int bid  = blockIdx.x;
    const int dirb = bid & 7;              // low bits: one (dir,b) per XCD
    const int dir  = dirb >> 2;
    const int b    = dirb & 3;
    const int c0   = ((bid >> 3) & 1) * 128;
    const int i0   = (bid >> 4) * 64;

    const bf16* q = qg + ((size_t)dir*BB + b)*SS*DD + (size_t)i0*DD;
    const bf16* k = kg + ((size_t)(1-dir)*BB + b)*SS*DD;
    const bf16* v = vg + ((size_t)(1-dir)*BB + b)*CC*SS;
    float* op = out + ((size_t)dir*BB + b)*CC*SS;

    // Q as B-frag: B[n=q(ln)][k=d(quad*8+)]  (wave's 16 queries)
    const bf16x8 b_q = *(const bf16x8*)(q + (size_t)(w*16 + ln)*DD + quad*8);
    // K as A-frag base: A[m=key(ln)][k=d(quad*8+)]
    const bf16* kbase = k + (size_t)ln*DD + quad*8;
    const bf16* vptr[2];
    #pragma unroll
    for (int cb = 0; cb < 2; ++cb)
        vptr[cb] = v + (size_t)(c0 + w*32 + cb*16 + ln)*SS + quad*8;

    f32x4 o[4][2];
    #pragma unroll
    for (int qb = 0; qb < 4; ++qb)
        #pragma unroll
        for (int cb = 0; cb < 2; ++cb) o[qb][cb] = (f32x4){0.f,0.f,0.f,0.f};
    f32x4 lpv = (f32x4){0.f,0.f,0.f,0.f};

    const int swz  = ln & 7;
    const int prow = (w*16 + ln)*64;

    // single-set fragments, prefetch-after-use (distance ~1 iter)
    bf16x8 kf[4], vf[2][2];
    {
        #pragma unroll
        for (int nb = 0; nb < 4; ++nb)
            kf[nb] = *(const bf16x8*)(kbase + (size_t)(nb*16)*DD);
        #pragma unroll
        for (int ks = 0; ks < 2; ++ks)
            #pragma unroll
            for (int cb = 0; cb < 2; ++cb)
                vf[ks][cb] = *(const bf16x8*)(vptr[cb] + ks*32);
        // prologue: S^T(0) + softmax(0) -> buf0
        f32x4 s[4];
        #pragma unroll
        for (int nb = 0; nb < 4; ++nb)
            s[nb] = __builtin_amdgcn_mfma_f32_16x16x32_bf16(
                        kf[nb], b_q, (f32x4){0.f,0.f,0.f,0.f}, 0, 0, 0);
        #pragma unroll
        for (int nb = 0; nb < 4; ++nb)
            kf[nb] = *(const bf16x8*)(kbase + (size_t)(64 + nb*16)*DD);
        #pragma unroll
        for (int nb = 0; nb < 4; ++nb) {
            bf16x4 pk;
            #pragma unroll
            for (int r = 0; r < 4; ++r) {
                const float e = exp2f(s[nb][r]*L2E - SM_C);
                lpv[r] += e;
                pk[r] = (bf16)e;
            }
            *(bf16x4*)(p_s + prow + (((2*nb + (quad >> 1)) ^ swz) << 3)
                       + (quad & 1)*4) = pk;
        }
    }

    for (int n = 0; n < 64; ++n) {
        bar_lds();   // P(n) visible; pw buffer free (PV(n-1) done)
        const bf16* pr = p_s + (n & 1)*4096;
        bf16* pw = p_s + ((n + 1) & 1)*4096;

        f32x4 s[4];
        if (n < 63) {
            // S^T(n+1): kf holds K(n+1); co-issues with PV(n)
            #pragma unroll
            for (int nb = 0; nb < 4; ++nb)
                s[nb] = __builtin_amdgcn_mfma_f32_16x16x32_bf16(
                            kf[nb], b_q, (f32x4){0.f,0.f,0.f,0.f}, 0, 0, 0);
            const int j2 = ((n + 2) << 6) & (SS - 1);
            #pragma unroll
            for (int nb = 0; nb < 4; ++nb)
                kf[nb] = *(const bf16x8*)(kbase + (size_t)(j2 + nb*16)*DD);
        }

        // PV(n)
        __builtin_amdgcn_s_setprio(1);
        #pragma unroll
        for (int ks = 0; ks < 2; ++ks) {
            bf16x8 ap[4];
            #pragma unroll
            for (int qb = 0; qb < 4; ++qb)
                ap[qb] = *(const bf16x8*)(pr + (qb*16 + ln)*64
                                          + (((ks*4 + quad) ^ swz) << 3));
            #pragma unroll
            for (int qb = 0; qb < 4; ++qb)
                #pragma unroll
                for (int cb = 0; cb < 2; ++cb)
                    o[qb][cb] = __builtin_amdgcn_mfma_f32_16x16x32_bf16(
                                    ap[qb], vf[ks][cb], o[qb][cb], 0, 0, 0);
        }
        __builtin_amdgcn_s_setprio(0);

        // vf <- V(n+1) (used next iter; gap covered by softmax+bar+S^T + TLP)
        const int j1 = ((n + 1) << 6) & (SS - 1);
        #pragma unroll
        for (int ks = 0; ks < 2; ++ks)
            #pragma unroll
            for (int cb = 0; cb < 2; ++cb)
                vf[ks][cb] = *(const bf16x8*)(vptr[cb] + j1 + ks*32);

        if (n < 63) {
            // softmax(n+1) -> pw (S-mfma results long ready)
            #pragma unroll
            for (int nb = 0; nb < 4; ++nb) {
                bf16x4 pk;
                #pragma unroll
                for (int r = 0; r < 4; ++r) {
                    const float e = exp2f(s[nb][r]*L2E - SM_C);
                    lpv[r] += e;
                    pk[r] = (bf16)e;
                }
                *(bf16x4*)(pw + prow + (((2*nb + (quad >> 1)) ^ swz) << 3)
                           + (quad & 1)*4) = pk;
            }
        }
    }

    // l: lane covers keys {*, nb*16+quad*4+r} for query w*16+ln -> reduce quads
    float lp = (lpv[0] + lpv[1]) + (lpv[2] + lpv[3]);
    lp += __shfl_xor(lp, 16);
    lp += __shfl_xor(lp, 32);
    if (lane < 16) l_s[w*16 + ln] = lp;
    __syncthreads();

    // epilogue: normalize + direct coalesced stores
    #pragma unroll
    for (int qb = 0; qb < 4; ++qb) {
        const f32x4 lq = *(const f32x4*)(l_s + qb*16 + quad*4);
        const float ri0 = 1.0f/lq[0], ri1 = 1.0f/lq[1], ri2 = 1.0f/lq[2], ri3 = 1.0f/lq[3];
        #pragma unroll
        for (int cb = 0; cb < 2; ++cb) {
            const int c = c0 + w*32 + cb*16 + ln;
            float4 val = make_float4(o[qb][cb][0]*ri0, o[qb][cb][1]*ri1,
                                     o[qb][cb][2]*ri2, o[qb][cb][3]*ri3);
            *(float4*)(op + (size_t)c*SS + i0 + qb*16 + quad*4) = val;
        }
    }
}

// ------------------------------------------------- launch
extern "C" void kernel_launch(void* const* d_in, const int* in_sizes, int n_in,
                              void* d_out, int out_size, void* d_ws, size_t ws_size,
                              hipStream_t stream)
{
    const float* x  = (const float*)d_in[0];
    const float* y  = (const float*)d_in[1];
    const float* Wq = (const float*)d_in[2];
    const float* bq = (const float*)d_in[3];
    const float* Wk = (const float*)d_in[4];
    const float* bk = (const float*)d_in[5];
    const float* Wv = (const float*)d_in[6];
    const float* bv = (const float*)d_in[7];
    float* out = (float*)d_out;
    bf16* ws   = (bf16*)d_ws;

    bf16* qw = ws + Q_OFF;
    bf16* kw = ws + K_OFF;
    bf16* vw = ws + V_OFF;
    bf16* wb = ws + WB_OFF;

    convert_w_kernel<<<40,   256, 0, stream>>>(Wq, Wk, Wv, wb);
    proj_all_kernel <<<512,  256, 0, stream>>>(x, y, wb, bq, bk, bv, qw, kw, vw);
    attn_kernel     <<<1024, 256, 0, stream>>>(qw, kw, vw, out);
}

// Round 4
// 258.443 us; speedup vs baseline: 1.0977x; 1.0977x over previous
//
#include <hip/hip_runtime.h>

#define BB 4
#define CC 256
#define DD 32
#define SS 4096

typedef __bf16 bf16;
typedef __bf16 bf16x8 __attribute__((ext_vector_type(8)));
typedef __bf16 bf16x4 __attribute__((ext_vector_type(4)));
typedef float f32x4 __attribute__((ext_vector_type(4)));
typedef unsigned int u32;
typedef unsigned short u16;

// workspace layout (bf16 elements):
//  q:  [2][BB][SS][DD]  off 0         (pos-major, 32 d inner)
//  k:  [2][BB][SS][DD]  off 1048576
//  v:  [2][BB][CC][SS]  off 2097152   (c-major, pos inner)
//  wb: [320][CC]        off 10485760  (bf16 Wq|Wk|Wv stacked)
#define Q_OFF  0
#define K_OFF  1048576
#define V_OFF  2097152
#define WB_OFF 10485760

static __device__ __forceinline__ u32 pack2(float lo, float hi) {
    bf16 a = (bf16)lo, b = (bf16)hi;
    u16 ua = __builtin_bit_cast(u16, a), ub = __builtin_bit_cast(u16, b);
    return (u32)ua | ((u32)ub << 16);
}

// LDS-only barrier: drain ds ops, sync, but let global loads stay in flight
// (__syncthreads emits s_waitcnt vmcnt(0) which defeats register prefetch).
static __device__ __forceinline__ void bar_lds() {
    asm volatile("s_waitcnt lgkmcnt(0)" ::: "memory");
    __builtin_amdgcn_s_barrier();
    asm volatile("" ::: "memory");
}

// ------------------------------------------------- W fp32 -> bf16 [320][256]
__global__ __launch_bounds__(256) void convert_w_kernel(
    const float* __restrict__ Wq, const float* __restrict__ Wk,
    const float* __restrict__ Wv, bf16* __restrict__ wb)
{
    const int gid = blockIdx.x*256 + threadIdx.x;    // 40 blocks -> 10240
    const int idx = gid*8;
    const int o = idx >> 8, cc = idx & 255;
    const float* row = (o < 32) ? (Wq + (size_t)o*CC)
                     : (o < 64) ? (Wk + (size_t)(o-32)*CC)
                                : (Wv + (size_t)(o-64)*CC);
    const float4 a = *(const float4*)(row + cc);
    const float4 c = *(const float4*)(row + cc + 4);
    bf16x8 pk;
    pk[0]=(bf16)a.x; pk[1]=(bf16)a.y; pk[2]=(bf16)a.z; pk[3]=(bf16)a.w;
    pk[4]=(bf16)c.x; pk[5]=(bf16)c.y; pk[6]=(bf16)c.z; pk[7]=(bf16)c.w;
    *(bf16x8*)(wb + idx) = pk;
}

// ------------------------------------------------- fused q,k,v projection (MFMA)
// C[pos][o] = sum_cc X[cc][pos]*W[o][cc] + bias;  o: 0-31 q, 32-63 k, 64-319 v
// Double-buffered xT + register X-prefetch; bar_lds (no vmcnt drain) keeps the
// global prefetches in flight across the per-chunk barrier.
__global__ __launch_bounds__(256, 2) void proj_all_kernel(
    const float* __restrict__ x, const float* __restrict__ y,
    const bf16* __restrict__ wb,
    const float* __restrict__ bq, const float* __restrict__ bk,
    const float* __restrict__ bv,
    bf16* __restrict__ qout, bf16* __restrict__ kout, bf16* __restrict__ vout)
{
    // xT: [2][64 pos][40 bf16] (row 80 B, 16B-aligned)
    __shared__ __align__(16) char smem[2*5120];
    bf16* xT  = (bf16*)smem;
    u32*  xTw = (u32*)smem;

    const int t    = threadIdx.x;
    const int lane = t & 63;
    const int w    = t >> 6;
    const int ln   = lane & 15;
    const int quad = lane >> 4;

    const int bid  = blockIdx.x;
    const int dirb = bid & 7;
    const int src  = dirb >> 2;
    const int b    = dirb & 3;
    const int i0   = (bid >> 3) * 64;
    const float* in = src ? y : x;
    const float* xbase = in + (size_t)b*CC*SS + i0;

    const int cp = t >> 4;            // cc-pair 0..15 -> cc {2cp, 2cp+1}
    const int pq = (t & 15) * 4;      // pos 0..60

    float bias[5];
    #pragma unroll
    for (int nbl = 0; nbl < 5; ++nbl) {
        const int o = 80*w + nbl*16 + ln;
        bias[nbl] = (o < 32) ? bq[o] : (o < 64) ? bk[o-32] : bv[o-64];
    }
    f32x4 acc[4][5];
    #pragma unroll
    for (int mb = 0; mb < 4; ++mb)
        #pragma unroll
        for (int nbl = 0; nbl < 5; ++nbl)
            acc[mb][nbl] = (f32x4){bias[nbl], bias[nbl], bias[nbl], bias[nbl]};

    const bf16* wrow = wb + (size_t)(80*w + ln)*CC + quad*8;
    bf16x8 bf[5];
    #pragma unroll
    for (int nbl = 0; nbl < 5; ++nbl)
        bf[nbl] = *(const bf16x8*)(wrow + (size_t)nbl*16*CC);

    // stage chunk 0 into buf0
    {
        const float* r0 = xbase + (size_t)(2*cp)*SS + pq;
        const float4 a0 = *(const float4*)r0;
        const float4 a1 = *(const float4*)(r0 + SS);
        xTw[(pq+0)*20 + cp] = pack2(a0.x, a1.x);
        xTw[(pq+1)*20 + cp] = pack2(a0.y, a1.y);
        xTw[(pq+2)*20 + cp] = pack2(a0.z, a1.z);
        xTw[(pq+3)*20 + cp] = pack2(a0.w, a1.w);
    }
    // prefetch chunk 1 into regs
    float4 a0, a1;
    {
        const float* r1 = xbase + (size_t)(32 + 2*cp)*SS + pq;
        a0 = *(const float4*)r1;
        a1 = *(const float4*)(r1 + SS);
    }
    bar_lds();

    for (int n = 0; n < 8; ++n) {
        bf16x8 af[4];
        #pragma unroll
        for (int mb = 0; mb < 4; ++mb)
            af[mb] = *(const bf16x8*)(xT + (n&1)*2560 + (mb*16 + ln)*40 + quad*8);
        // write prefetched chunk n+1 into other buffer
        if (n < 7) {
            u32* dst = xTw + ((n+1)&1)*1280;
            dst[(pq+0)*20 + cp] = pack2(a0.x, a1.x);
            dst[(pq+1)*20 + cp] = pack2(a0.y, a1.y);
            dst[(pq+2)*20 + cp] = pack2(a0.z, a1.z);
            dst[(pq+3)*20 + cp] = pack2(a0.w, a1.w);
        }
        // prefetch chunk n+2 regs (wrap keeps loads in-bounds; redundant at tail)
        {
            const int cc2 = ((n+2)*32) & 255;
            const float* r2 = xbase + (size_t)(cc2 + 2*cp)*SS + pq;
            a0 = *(const float4*)r2;
            a1 = *(const float4*)(r2 + SS);
        }
        #pragma unroll
        for (int mb = 0; mb < 4; ++mb)
            #pragma unroll
            for (int nbl = 0; nbl < 5; ++nbl)
                acc[mb][nbl] = __builtin_amdgcn_mfma_f32_16x16x32_bf16(
                                   af[mb], bf[nbl], acc[mb][nbl], 0, 0, 0);
        // prefetch next W chunk
        const int ccn = ((n+1)*32) & 255;
        #pragma unroll
        for (int nbl = 0; nbl < 5; ++nbl)
            bf[nbl] = *(const bf16x8*)(wrow + (size_t)nbl*16*CC + ccn);
        bar_lds();
    }

    bf16* qo = qout + (size_t)(src*BB + b)*SS*DD;
    bf16* ko = kout + (size_t)(src*BB + b)*SS*DD;
    bf16* vo = vout + (size_t)(src*BB + b)*CC*SS;
    #pragma unroll
    for (int nbl = 0; nbl < 5; ++nbl) {
        const int o = 80*w + nbl*16 + ln;
        if (o < 32) {
            #pragma unroll
            for (int mb = 0; mb < 4; ++mb)
                #pragma unroll
                for (int r = 0; r < 4; ++r)
                    qo[(size_t)(i0 + mb*16 + quad*4 + r)*DD + o] = (bf16)acc[mb][nbl][r];
        } else if (o < 64) {
            #pragma unroll
            for (int mb = 0; mb < 4; ++mb)
                #pragma unroll
                for (int r = 0; r < 4; ++r)
                    ko[(size_t)(i0 + mb*16 + quad*4 + r)*DD + (o-32)] = (bf16)acc[mb][nbl][r];
        } else {
            const int c = o - 64;
            #pragma unroll
            for (int mb = 0; mb < 4; ++mb) {
                bf16x4 pk;
                #pragma unroll
                for (int r = 0; r < 4; ++r) pk[r] = (bf16)acc[mb][nbl][r];
                *(bf16x4*)(vo + (size_t)c*SS + i0 + mb*16 + quad*4) = pk;
            }
        }
    }
}

// ------------------------------------------------- attention (flag-synced ring)
// Block: 64 queries x 256 c. Wave w: produces S^T+softmax for queries
// [16w,16w+16) of chunk n+2, consumes full P of chunk n for PV c-range
// [64w,64w+64). P lives in a 4-slot LDS ring with monotone ready/free counters
// (LDS atomics + spin) — ZERO barriers in the main loop. The per-iter block
// barrier was phase-locking all waves (MFMA burst / softmax burst / load-wait
// executed serially, each pipe <20% busy); flag sync lets waves drift +-2
// chunks so pipes overlap across waves. Deadlock-safe: counters monotone,
// ring depth 4 > produce-ahead 2, prologue chunks 0/1 need no free-wait.
#define SM_M  16.0f
#define L2E   1.4426950408889634f
#define SM_C  (SM_M * L2E)

__global__ __launch_bounds__(256, 2) void attn_kernel(
    const bf16* __restrict__ qg, const bf16* __restrict__ kg,
    const bf16* __restrict__ vg, float* __restrict__ out)
{
    __shared__ __align__(16) char smem[33056];
    bf16*  p_s = (bf16*)smem;                 // [4][64][64] swizzled ring
    float* l_s = (float*)(smem + 32768);      // [64]
    u32*   flg = (u32*)(smem + 33024);        // [0..3] ready, [4..7] free

    const int t    = threadIdx.x;
    const int lane = t & 63;
    const int w    = t >> 6;
    const int ln   = lane & 15;
    const int quad = lane >> 4;

    if (t < 8) flg[t] = 0;

    const int bid  = blockIdx.x;
    const int dirb = bid & 7;              // low bits: one (dir,b) per XCD
    const int dir  = dirb >> 2;
    const int b    = dirb & 3;
    const int i0   = (bid >> 3) * 64;

    const bf16* q = qg + ((size_t)dir*BB + b)*SS*DD + (size_t)i0*DD;
    const bf16* k = kg + ((size_t)(1-dir)*BB + b)*SS*DD;
    const bf16* v = vg + ((size_t)(1-dir)*BB + b)*CC*SS;
    float* op = out + ((size_t)dir*BB + b)*CC*SS;

    // Q as B-frag: B[n=q(ln)][k=d(quad*8+)]  (wave's 16 queries)
    const bf16x8 b_q = *(const bf16x8*)(q + (size_t)(w*16 + ln)*DD + quad*8);
    // K as A-frag base: A[m=key(ln)][k=d(quad*8+)]
    const bf16* kbase = k + (size_t)ln*DD + quad*8;
    const bf16* vptr[4];
    #pragma unroll
    for (int cb = 0; cb < 4; ++cb)
        vptr[cb] = v + (size_t)(w*64 + cb*16 + ln)*SS + quad*8;

    f32x4 o[4][4];
    #pragma unroll
    for (int qb = 0; qb < 4; ++qb)
        #pragma unroll
        for (int cb = 0; cb < 4; ++cb) o[qb][cb] = (f32x4){0.f,0.f,0.f,0.f};
    f32x4 lpv = (f32x4){0.f,0.f,0.f,0.f};

    const int swz  = ln & 7;
    const int prow = (w*16 + ln)*64;

    // spin until counter >= target (monotone; usually instant)
    auto wait_ge = [&](u32* p, u32 tgt) {
        while (__hip_atomic_load(p, __ATOMIC_RELAXED,
                                 __HIP_MEMORY_SCOPE_WORKGROUP) < tgt)
            __builtin_amdgcn_s_sleep(1);
        asm volatile("" ::: "memory");
    };
    // softmax s -> P slot, then publish (ds writes drained before flag add)
    auto emit_p = [&](int slot, const f32x4* s) {
        bf16* pw = p_s + slot*4096;
        #pragma unroll
        for (int nb = 0; nb < 4; ++nb) {
            bf16x4 pk;
            #pragma unroll
            for (int r = 0; r < 4; ++r) {
                const float e = exp2f(s[nb][r]*L2E - SM_C);
                lpv[r] += e;
                pk[r] = (bf16)e;
            }
            *(bf16x4*)(pw + prow + (((2*nb + (quad >> 1)) ^ swz) << 3)
                       + (quad & 1)*4) = pk;
        }
        asm volatile("s_waitcnt lgkmcnt(0)" ::: "memory");
        if (lane == 0)
            __hip_atomic_fetch_add(&flg[slot], 1u, __ATOMIC_RELAXED,
                                   __HIP_MEMORY_SCOPE_WORKGROUP);
    };

    bf16x8 kf[4], vf[2][4];
    #pragma unroll
    for (int nb = 0; nb < 4; ++nb)
        kf[nb] = *(const bf16x8*)(kbase + (size_t)(nb*16)*DD);
    #pragma unroll
    for (int ks = 0; ks < 2; ++ks)
        #pragma unroll
        for (int cb = 0; cb < 4; ++cb)
            vf[ks][cb] = *(const bf16x8*)(vptr[cb] + ks*32);

    __syncthreads();   // flag init visible; only barrier before epilogue

    // prologue: produce chunks 0,1 (slots 0,1; no free-wait needed)
    {
        f32x4 s[4];
        #pragma unroll
        for (int nb = 0; nb < 4; ++nb)
            s[nb] = __builtin_amdgcn_mfma_f32_16x16x32_bf16(
                        kf[nb], b_q, (f32x4){0.f,0.f,0.f,0.f}, 0, 0, 0);
        #pragma unroll
        for (int nb = 0; nb < 4; ++nb)
            kf[nb] = *(const bf16x8*)(kbase + (size_t)(64 + nb*16)*DD);
        emit_p(0, s);
        #pragma unroll
        for (int nb = 0; nb < 4; ++nb)
            s[nb] = __builtin_amdgcn_mfma_f32_16x16x32_bf16(
                        kf[nb], b_q, (f32x4){0.f,0.f,0.f,0.f}, 0, 0, 0);
        #pragma unroll
        for (int nb = 0; nb < 4; ++nb)
            kf[nb] = *(const bf16x8*)(kbase + (size_t)(128 + nb*16)*DD);
        emit_p(1, s);
    }

    for (int n = 0; n < 64; ++n) {
        const int sl = n & 3;
        f32x4 s[4];
        const int n2 = n + 2;
        if (n < 62) {
            // slot for chunk n+2 free when chunk n-2 consumed by all 4 waves
            wait_ge(&flg[4 + (n2 & 3)], (u32)((n2 >> 2) * 4));
            #pragma unroll
            for (int nb = 0; nb < 4; ++nb)
                s[nb] = __builtin_amdgcn_mfma_f32_16x16x32_bf16(
                            kf[nb], b_q, (f32x4){0.f,0.f,0.f,0.f}, 0, 0, 0);
            const int j3 = ((n + 3) << 6) & (SS - 1);
            #pragma unroll
            for (int nb = 0; nb < 4; ++nb)
                kf[nb] = *(const bf16x8*)(kbase + (size_t)(j3 + nb*16)*DD);
        }
        // chunk n ready when all 4 waves produced their q-quarter
        wait_ge(&flg[sl], (u32)(((n >> 2) + 1) * 4));
        const bf16* pr = p_s + sl*4096;

        __builtin_amdgcn_s_setprio(1);
        #pragma unroll
        for (int ks = 0; ks < 2; ++ks) {
            bf16x8 ap[4];
            #pragma unroll
            for (int qb = 0; qb < 4; ++qb)
                ap[qb] = *(const bf16x8*)(pr + (qb*16 + ln)*64
                                          + (((ks*4 + quad) ^ swz) << 3));
            #pragma unroll
            for (int qb = 0; qb < 4; ++qb)
                #pragma unroll
                for (int cb = 0; cb < 4; ++cb)
                    o[qb][cb] = __builtin_amdgcn_mfma_f32_16x16x32_bf16(
                                    ap[qb], vf[ks][cb], o[qb][cb], 0, 0, 0);
        }
        __builtin_amdgcn_s_setprio(0);

        // vf <- V(n+1) (global, vmcnt — stays in flight past the ds drain)
        const int j1 = ((n + 1) << 6) & (SS - 1);
        #pragma unroll
        for (int ks = 0; ks < 2; ++ks)
            #pragma unroll
            for (int cb = 0; cb < 4; ++cb)
                vf[ks][cb] = *(const bf16x8*)(vptr[cb] + j1 + ks*32);

        // release slot: our ap ds_reads have retired into registers
        asm volatile("s_waitcnt lgkmcnt(0)" ::: "memory");
        if (lane == 0)
            __hip_atomic_fetch_add(&flg[4 + sl], 1u, __ATOMIC_RELAXED,
                                   __HIP_MEMORY_SCOPE_WORKGROUP);

        if (n < 62)
            emit_p(n2 & 3, s);   // softmax(n+2) -> ring, publish
    }

    // l: lane covers keys {*, nb*16+quad*4+r} for query w*16+ln -> reduce quads
    float lp = (lpv[0] + lpv[1]) + (lpv[2] + lpv[3]);
    lp += __shfl_xor(lp, 16);
    lp += __shfl_xor(lp, 32);
    if (lane < 16) l_s[w*16 + ln] = lp;
    __syncthreads();

    // epilogue: normalize + direct coalesced stores
    #pragma unroll
    for (int qb = 0; qb < 4; ++qb) {
        const f32x4 lq = *(const f32x4*)(l_s + qb*16 + quad*4);
        const float ri0 = 1.0f/lq[0], ri1 = 1.0f/lq[1], ri2 = 1.0f/lq[2], ri3 = 1.0f/lq[3];
        #pragma unroll
        for (int cb = 0; cb < 4; ++cb) {
            const int c = w*64 + cb*16 + ln;
            float4 val = make_float4(o[qb][cb][0]*ri0, o[qb][cb][1]*ri1,
                                     o[qb][cb][2]*ri2, o[qb][cb][3]*ri3);
            *(float4*)(op + (size_t)c*SS + i0 + qb*16 + quad*4) = val;
        }
    }
}

// ------------------------------------------------- launch
extern "C" void kernel_launch(void* const* d_in, const int* in_sizes, int n_in,
                              void* d_out, int out_size, void* d_ws, size_t ws_size,
                              hipStream_t stream)
{
    const float* x  = (const float*)d_in[0];
    const float* y  = (const float*)d_in[1];
    const float* Wq = (const float*)d_in[2];
    const float* bq = (const float*)d_in[3];
    const float* Wk = (const float*)d_in[4];
    const float* bk = (const float*)d_in[5];
    const float* Wv = (const float*)d_in[6];
    const float* bv = (const float*)d_in[7];
    float* out = (float*)d_out;
    bf16* ws   = (bf16*)d_ws;

    bf16* qw = ws + Q_OFF;
    bf16* kw = ws + K_OFF;
    bf16* vw = ws + V_OFF;
    bf16* wb = ws + WB_OFF;

    convert_w_kernel<<<40,  256, 0, stream>>>(Wq, Wk, Wv, wb);
    proj_all_kernel <<<512, 256, 0, stream>>>(x, y, wb, bq, bk, bv, qw, kw, vw);
    attn_kernel     <<<512, 256, 0, stream>>>(qw, kw, vw, out);
}